// Round 6
// baseline (4773.045 us; speedup 1.0000x reference)
//
#include <hip/hip_runtime.h>
#include <math.h>

#define NPTS 1024
#define BB 2
#define KNN 20
#define ROWS 2048
#define CATC 960
#define TT 3
#define GRID 512
typedef unsigned long long ull;
typedef __attribute__((ext_vector_type(8))) short bf16x8;
typedef __attribute__((ext_vector_type(4))) float f32x4;

__device__ __forceinline__ float lrelu_f(float x){ return x >= 0.f ? x : 0.2f*x; }

__device__ __forceinline__ unsigned short f2bf(float f){
  unsigned u = __float_as_uint(f);
  return (unsigned short)((u + 0x7FFFu + ((u >> 16) & 1u)) >> 16);
}
__device__ __forceinline__ float bf2f(unsigned short h){
  return __uint_as_float(((unsigned)h) << 16);
}

// ===================== grid barrier (device-scope, all blocks co-resident) =====================
__device__ __forceinline__ void gbar(unsigned* flags, unsigned* gen, unsigned g){
  __syncthreads();
  __threadfence();
  const int bid = blockIdx.x, tid = threadIdx.x;
  if (bid == 0){
    for (int i = tid; i < GRID; i += 256){
      if (i != 0)
        while (__hip_atomic_load(&flags[i], __ATOMIC_ACQUIRE, __HIP_MEMORY_SCOPE_AGENT) < g)
          __builtin_amdgcn_s_sleep(2);
    }
    __syncthreads();
    if (tid == 0)
      __hip_atomic_store(gen, g, __ATOMIC_RELEASE, __HIP_MEMORY_SCOPE_AGENT);
  } else {
    if (tid == 0){
      __hip_atomic_store(&flags[bid], g, __ATOMIC_RELEASE, __HIP_MEMORY_SCOPE_AGENT);
      while (__hip_atomic_load(gen, __ATOMIC_ACQUIRE, __HIP_MEMORY_SCOPE_AGENT) < g)
        __builtin_amdgcn_s_sleep(2);
    }
    __syncthreads();
  }
  __threadfence();
}

// ===================== fp32 GEMM (conv0 only, K=3) =====================
__device__ __forceinline__ void gemm_dev(const float* __restrict__ A, int lda,
    const float* __restrict__ B, int ldb, float* __restrict__ C, int ldc,
    int K, int kb, int bm, int bn, int tid, float* sm)
{
  float (*As)[68] = (float(*)[68])sm;
  float (*Bs)[68] = (float(*)[68])(sm + 16*68);
  const int tx = tid & 15, ty = tid >> 4;
  const int lr = tid >> 2, kq = tid & 3;
  float acc[4][4] = {};
  for (int k0 = 0; k0 < K; k0 += 16) {
#pragma unroll
    for (int e=0;e<4;++e){
      int gk = k0 + kq*4 + e;
      As[kq*4+e][lr] = (gk<K)? A[(size_t)(bm+lr)*lda+kb+gk] : 0.f;
      Bs[kq*4+e][lr] = (gk<K)? B[(size_t)(bn+lr)*ldb+kb+gk] : 0.f;
    }
    __syncthreads();
#pragma unroll
    for (int kk = 0; kk < 16; ++kk) {
      float4 a4 = *(const float4*)&As[kk][ty*4];
      float4 b4 = *(const float4*)&Bs[kk][tx*4];
      float ar[4]={a4.x,a4.y,a4.z,a4.w}, br[4]={b4.x,b4.y,b4.z,b4.w};
#pragma unroll
      for (int i=0;i<4;++i)
#pragma unroll
        for (int j=0;j<4;++j) acc[i][j]=fmaf(ar[i],br[j],acc[i][j]);
    }
    __syncthreads();
  }
#pragma unroll
  for (int i=0;i<4;++i){
    float4 v; v.x=acc[i][0]; v.y=acc[i][1]; v.z=acc[i][2]; v.w=acc[i][3];
    *(float4*)&C[(size_t)(bm+ty*4+i)*ldc + bn + tx*4] = v;
  }
}

// ===================== MFMA bf16 3-split GEMM: LDS-free, 64x64 WG tile =====================
__device__ __forceinline__ void mfma_dev(const short* __restrict__ A, int lda,
    const short* __restrict__ B3, size_t sStride, int ldb,
    float* __restrict__ C, int ldc, int K, int kb, int bm, int bn, int tid)
{
  const int wave = tid >> 6, lane = tid & 63;
  const int wm = (wave >> 1) << 5, wn = (wave & 1) << 5;
  const int rr = lane & 15, kq = (lane >> 4) << 3;
  f32x4 acc[2][2] = {};
  const short* Ap = A + (size_t)(bm + wm + rr)*lda + kb + kq;
  const short* Bp = B3 + (size_t)(bn + wn + rr)*ldb + kb + kq;
  for (int k0 = 0; k0 < K; k0 += 32) {
    bf16x8 a0 = *(const bf16x8*)(Ap + k0);
    bf16x8 a1 = *(const bf16x8*)(Ap + (size_t)16*lda + k0);
#pragma unroll
    for (int s = 0; s < 3; ++s) {
      bf16x8 b0 = *(const bf16x8*)(Bp + (size_t)s*sStride + k0);
      bf16x8 b1 = *(const bf16x8*)(Bp + (size_t)s*sStride + (size_t)16*ldb + k0);
      acc[0][0] = __builtin_amdgcn_mfma_f32_16x16x32_bf16(a0, b0, acc[0][0], 0, 0, 0);
      acc[0][1] = __builtin_amdgcn_mfma_f32_16x16x32_bf16(a0, b1, acc[0][1], 0, 0, 0);
      acc[1][0] = __builtin_amdgcn_mfma_f32_16x16x32_bf16(a1, b0, acc[1][0], 0, 0, 0);
      acc[1][1] = __builtin_amdgcn_mfma_f32_16x16x32_bf16(a1, b1, acc[1][1], 0, 0, 0);
    }
  }
  const int drb = (lane >> 4) << 2;
#pragma unroll
  for (int i = 0; i < 2; ++i)
#pragma unroll
    for (int j = 0; j < 2; ++j)
#pragma unroll
      for (int t = 0; t < 4; ++t)
        C[(size_t)(bm + wm + i*16 + drb + t)*ldc + bn + wn + j*16 + rr] = acc[i][j][t];
}

// ============ wave-level popcount KNN ============
template<int W>
__device__ __forceinline__ void knn_wave(const ull* __restrict__ pk, int* __restrict__ idx,
                                         int row, int lane)
{
  const int n = row & (NPTS-1), b = row >> 10;
  const ull* pb = pk + (size_t)b*NPTS*W;
  ull cw[W]; int pn = 0;
#pragma unroll
  for (int w=0; w<W; ++w){ cw[w] = pb[(size_t)n*W + w]; pn += __popcll(cw[w]); }
  unsigned keys[16];
#pragma unroll 4
  for (int i=0;i<16;++i){
    int m = lane + (i<<6);
    int inner=0, pm=0;
#pragma unroll
    for (int w=0;w<W;++w){
      ull rm = pb[(size_t)m*W + w];
      inner += __popcll(rm & cw[w]);
      pm    += __popcll(rm);
    }
    int d = 2*inner - pn - pm;
    keys[i] = ((unsigned)(d+1024)<<11) | (unsigned)(NPTS-1-m);
  }
  unsigned lmax = keys[0];
#pragma unroll
  for (int i=1;i<16;++i) lmax = keys[i]>lmax ? keys[i] : lmax;
  unsigned mywin = 0;
  for (int s=0;s<KNN;++s){
    unsigned v = lmax;
#pragma unroll
    for (int off=1; off<64; off<<=1){ unsigned o = __shfl_xor(v, off, 64); if (o>v) v=o; }
    if (lane == s) mywin = (unsigned)(NPTS-1) - (v & 0x7FFu);
    if (lmax == v){
#pragma unroll
      for (int i=0;i<16;++i) if (keys[i]==v) keys[i]=0u;
      lmax = keys[0];
#pragma unroll
      for (int i=1;i<16;++i) lmax = keys[i]>lmax ? keys[i] : lmax;
    }
  }
  if (lane < KNN) idx[(size_t)row*KNN + lane] = (int)mywin;
}

// ============ wave-level layer-0 KNN (fp32, exact ref op order) ============
__device__ __forceinline__ void knn0_wave(const float* __restrict__ x, const float* __restrict__ x2,
                                          int* __restrict__ idx, int row, int lane)
{
  const int n = row & (NPTS-1), b = row >> 10;
  const float* xb = x + (size_t)b*3*NPTS;
  float fn0 = xb[n], fn1 = xb[NPTS+n], fn2 = xb[2*NPTS+n];
  float x2n = x2[row];
  ull keys[16];
#pragma unroll 4
  for (int i=0;i<16;++i){
    int m = lane + (i<<6);
    float inner = __fadd_rn(__fadd_rn(__fmul_rn(fn0, xb[m]), __fmul_rn(fn1, xb[NPTS+m])),
                            __fmul_rn(fn2, xb[2*NPTS+m]));
    float v = __fsub_rn(__fsub_rn(__fmul_rn(2.f, inner), x2n), x2[(b<<10)+m]);
    unsigned u = __float_as_uint(v);
    u = (u & 0x80000000u) ? ~u : (u | 0x80000000u);
    keys[i] = ((ull)u << 32) | (unsigned)(NPTS-1-m);
  }
  ull lmax = keys[0];
#pragma unroll
  for (int i=1;i<16;++i) lmax = keys[i]>lmax ? keys[i] : lmax;
  unsigned mywin = 0;
  for (int s=0;s<KNN;++s){
    ull v = lmax;
#pragma unroll
    for (int off=1; off<64; off<<=1){ ull o = __shfl_xor(v, off, 64); if (o>v) v=o; }
    if (lane == s) mywin = (unsigned)(NPTS-1) - (unsigned)(v & 0xFFFFFFFFull);
    if (lmax == v){
#pragma unroll
      for (int i=0;i<16;++i) if (keys[i]==v) keys[i]=0ull;
      lmax = keys[0];
#pragma unroll
      for (int i=1;i<16;++i) lmax = keys[i]>lmax ? keys[i] : lmax;
    }
  }
  if (lane < KNN) idx[(size_t)row*KNN + lane] = (int)mywin;
}

// ===================== BN+LIF =====================
__device__ __forceinline__ void bnlif_dev(int i, int oShift,
    const float* __restrict__ hmax, const double* __restrict__ S1, const double* __restrict__ S2,
    const float* __restrict__ g, const float* __restrict__ bb,
    const float* __restrict__ pmd, const float* __restrict__ pta,
    const float* __restrict__ prd, const float* __restrict__ ptb,
    float* __restrict__ stM, float* __restrict__ stT, float* __restrict__ stR,
    short* __restrict__ sout, int offOut, ull* __restrict__ pk, int init, int laneTid)
{
  int O = 1 << oShift;
  int bn = i >> oShift;
  int o  = i & (O - 1);
  double cnt = (double)ROWS * (double)KNN;
  double mu = S1[o] / cnt;
  double vv = S2[o] / cnt - mu*mu;
  float mean = (float)mu;
  float inv  = 1.f / sqrtf((float)vv + 1e-5f);
  float h = hmax[i];
  h = ((h - mean) * inv) * g[o] + bb[o];
  h = lrelu_f(h);
  float md = fminf(fmaxf(pmd[o], 0.1f), 0.99f);
  float ta = fminf(fmaxf(pta[o], 0.001f), 0.1f);
  float rd = fminf(fmaxf(prd[o], 0.1f), 0.95f);
  float tb = ptb[o];
  float M, T, R;
  if (init) { M = 0.f; T = tb; R = 0.f; }
  else      { M = stM[i]; T = stT[i]; R = stR[i]; }
  float xv = (R <= 0.f) ? h : 0.f;
  M = M * md * (1.f - R) + xv;
  float sp = (M - T > 0.f) ? 1.f : 0.f;
  M = M * (1.f - sp);
  R = R * rd + sp;
  T = tb + (T + ta*sp - tb) * 0.95f;
  stM[i] = M; stT[i] = T; stR[i] = R;
  sout[(size_t)bn*CATC + offOut + o] = (sp != 0.f) ? (short)0x3F80 : (short)0;
  ull ball = __ballot(sp != 0.f);
  if ((laneTid & 63) == 0) pk[i >> 6] = ball;
}

// ===================== gather: 4 rows per virtual block =====================
__device__ __forceinline__ void gather4_dev(const float* __restrict__ AB, int O,
    const int* __restrict__ idx, float* __restrict__ hmax,
    double* __restrict__ S1, double* __restrict__ S2, int vb, int tid, int* sidx)
{
  int base = vb * 4;
  for (int i = tid; i < 4*KNN; i += 256) sidx[i] = idx[(size_t)base*KNN + i];
  __syncthreads();
  int twoO = 2*O;
  for (int o = tid; o < O; o += 256) {
    double ts1 = 0.0, ts2 = 0.0;
    for (int r = 0; r < 4; ++r) {
      int bn = base + r;
      int b = bn >> 10;
      float bc = AB[(size_t)bn*twoO + O + o];
      float mx = -INFINITY;
      double s1 = 0.0, s2 = 0.0;
#pragma unroll
      for (int k = 0; k < KNN; ++k) {
        int m = sidx[r*KNN + k];
        float a = AB[((size_t)(b*NPTS + m))*twoO + o];
        mx = fmaxf(mx, a);
        s1 += (double)a;
        s2 += (double)a * (double)a;
      }
      hmax[(size_t)bn*O + o] = mx - bc;
      ts1 += s1 - (double)KNN * (double)bc;
      ts2 += s2 - 2.0*(double)bc*s1 + (double)KNN*(double)bc*(double)bc;
    }
    atomicAdd(&S1[o], ts1);
    atomicAdd(&S2[o], ts2);
  }
  __syncthreads();
}

// ===================== aggregator finalize =====================
__device__ __forceinline__ void aggfin_dev(const float* __restrict__ pA, const float* __restrict__ pB,
    const float* __restrict__ gm, const float* __restrict__ bmv, float* __restrict__ pooled,
    int o, int tid, char* smraw)
{
  double* sd1 = (double*)smraw; double* sd2 = sd1 + 256;
  float* sm0 = (float*)(sd2 + 256); float* sm1 = sm0 + 256;
  double s1=0.0, s2=0.0; float m0=-INFINITY, m1=-INFINITY;
  for (int r=tid; r<ROWS; r+=256){
    float v = __fadd_rn(pA[(size_t)r*512+o], pB[(size_t)r*512+o]);
    s1 += (double)v; s2 += (double)v*(double)v;
    if (r < NPTS) m0 = fmaxf(m0, v); else m1 = fmaxf(m1, v);
  }
  sd1[tid]=s1; sd2[tid]=s2; sm0[tid]=m0; sm1[tid]=m1;
  __syncthreads();
  for (int off=128; off>0; off>>=1){
    if (tid<off){
      sd1[tid]+=sd1[tid+off]; sd2[tid]+=sd2[tid+off];
      sm0[tid]=fmaxf(sm0[tid],sm0[tid+off]);
      sm1[tid]=fmaxf(sm1[tid],sm1[tid+off]);
    }
    __syncthreads();
  }
  if (tid==0){
    double mean = sd1[0]/(double)ROWS;
    float var = (float)(sd2[0]/(double)ROWS - mean*mean);
    float m = (float)mean;
    float inv = 1.f/sqrtf(var + 1e-5f);
    pooled[o]       = lrelu_f(((sm0[0]-m)*inv)*gm[o] + bmv[o]);
    pooled[512 + o] = lrelu_f(((sm1[0]-m)*inv)*gm[o] + bmv[o]);
  }
  __syncthreads();
}

// ===================== setup pieces =====================
__device__ __forceinline__ void wsplit_dev(float w, short* dst, size_t NK, size_t e){
  unsigned short h1 = f2bf(w); float f1 = bf2f(h1);
  float r1 = w - f1;
  unsigned short h2 = f2bf(r1); float f2v = bf2f(h2);
  unsigned short h3 = f2bf(r1 - f2v);
  dst[e] = (short)h1; dst[NK + e] = (short)h2; dst[2*NK + e] = (short)h3;
}
__device__ __forceinline__ void wcatsplit_dev(const float* __restrict__ W, short* __restrict__ dst,
                                              int O, int C, size_t e){
  int rr = (int)(e / C), cc = (int)(e - (size_t)rr*C);
  float w = (rr < O) ? __fadd_rn(W[(size_t)rr*2*C + cc], W[(size_t)rr*2*C + C + cc])
                     : W[(size_t)(rr-O)*2*C + cc];
  wsplit_dev(w, dst, (size_t)2*O*C, e);
}

// ===================== mega arg struct =====================
struct MegaP {
  const float *x, *W0, *W1, *W2, *W3, *Wm;
  const float *g0,*b0,*g1,*b1,*g2,*b2,*g3,*b3;
  const float *gm,*bm,*tw,*lftb;
  const float *lp[4][4];
  float *f0,*x2;
  int *idx0,*idxS;
  float *AB,*hmax0,*hmaxS,*aggA,*aggB;
  short *scatH;
  double *S12_0,*S12;
  float *pooled;
  ull *pk0,*pk1,*pk2,*pk3;
  float *wc0;
  short *wcH1,*wcH2,*wcH3,*WmH;
  float *stM0,*stT0,*stR0,*stM1,*stT1,*stR1,*stM2,*stT2,*stR2,*stM3,*stT3,*stR3;
  float *out;
  unsigned *flags,*gen;
};

__device__ __forceinline__ void setup_vb(const MegaP& P, int vb, int tid){
  if (vb < 24) {
    int i = vb*256 + tid;
    int b = i / 3072, rem = i - b*3072, n = rem/3, c = rem - n*3;
    P.f0[i] = P.x[(size_t)b*3072 + c*NPTS + n];
  } else if (vb < 32) {
    int r = (vb-24)*256 + tid;
    int b = r >> 10, n = r & (NPTS-1);
    const float* xb = P.x + (size_t)b*3072;
    float a0=xb[n], a1=xb[NPTS+n], a2=xb[2*NPTS+n];
    P.x2[r] = __fadd_rn(__fadd_rn(__fmul_rn(a0,a0),__fmul_rn(a1,a1)),__fmul_rn(a2,a2));
  } else if (vb < 33) {
    for (int j=tid; j<1024; j+=256) P.S12_0[j]=0.0;
  } else if (vb < 35) {
    int i = (vb-33)*256+tid;
    if (i < 2*64*3){
      int r = i/3, c = i-r*3;
      P.wc0[i] = (r<64) ? __fadd_rn(P.W0[(size_t)r*6+c], P.W0[(size_t)r*6+3+c])
                        : P.W0[(size_t)(r-64)*6+c];
    }
  } else if (vb < 99)   { wcatsplit_dev(P.W1, P.wcH1, 128,  64, (size_t)(vb-35)*256+tid); }
  else if (vb < 355)    { wcatsplit_dev(P.W2, P.wcH2, 256, 128, (size_t)(vb-99)*256+tid); }
  else if (vb < 1379)   { wcatsplit_dev(P.W3, P.wcH3, 512, 256, (size_t)(vb-355)*256+tid); }
  else                  { size_t e = (size_t)(vb-1379)*256+tid; wsplit_dev(P.Wm[e], P.WmH, (size_t)512*960, e); }
}

// ===================== per-layer body (phases B,C,D) =====================
template<int W>
__device__ void layer_body(const MegaP& P, const ull* pk,
    const short* wcH, const float* gl, const float* bl,
    const float* pmd, const float* pta, const float* prd, const float* ptb,
    float* stM, float* stT, float* stR, ull* pkOut,
    int C, int O, int oShift, int offIn, int offOut, int init,
    unsigned& g, int bid, int tid, char* smem)
{
  // B: knn (512 vb) + conv MFMA tiles
  int twoO = 2*O, ntn = twoO/64, nvb = 512 + 32*ntn;
  const short* fin = P.scatH + offIn;
  size_t sStr = (size_t)twoO*C;
  for (int vb = bid; vb < nvb; vb += GRID){
    if (vb < 512){
      if (vb == 0){ for (int j=tid;j<1024;j+=256) P.S12[j]=0.0; }
      knn_wave<W>(pk, P.idxS, vb*4 + (tid>>6), tid&63);
    } else {
      int id = vb - 512, tm = id/ntn, tn = id - tm*ntn;
      mfma_dev(fin, CATC, wcH, sStr, C, P.AB, twoO, C, 0, tm*64, tn*64, tid);
    }
  }
  gbar(P.flags, P.gen, ++g);
  // C: gather
  for (int vb = bid; vb < 512; vb += GRID)
    gather4_dev(P.AB, O, P.idxS, P.hmaxS, P.S12, P.S12+512, vb, tid, (int*)smem);
  gbar(P.flags, P.gen, ++g);
  // D: bnlif
  int nb = (ROWS*O)/256;
  for (int vb = bid; vb < nb; vb += GRID)
    bnlif_dev(vb*256+tid, oShift, P.hmaxS, P.S12, P.S12+512, gl, bl,
              pmd, pta, prd, ptb, stM, stT, stR, P.scatH, offOut, pkOut, init, tid);
  gbar(P.flags, P.gen, ++g);
}

// ===================== THE mega kernel =====================
__global__ __launch_bounds__(256, 2) void k_mega(MegaP P)
{
  __shared__ __align__(16) char smem[8704];
  const int bid = blockIdx.x, tid = threadIdx.x;
  unsigned g = 0;

  // P0: setup
  for (int vb = bid; vb < 3299; vb += GRID) setup_vb(P, vb, tid);
  gbar(P.flags, P.gen, ++g);

  // P1: knn0 (512 vb) + conv0 (64 vb)
  for (int vb = bid; vb < 576; vb += GRID){
    if (vb < 512) knn0_wave(P.x, P.x2, P.idx0, vb*4 + (tid>>6), tid&63);
    else {
      int id = vb - 512;
      gemm_dev(P.f0, 3, P.wc0, 3, P.AB, 128, 3, 0, (id>>1)*64, (id&1)*64, tid, (float*)smem);
    }
  }
  gbar(P.flags, P.gen, ++g);

  // P2: gather0
  for (int vb = bid; vb < 512; vb += GRID)
    gather4_dev(P.AB, 64, P.idx0, P.hmax0, P.S12_0, P.S12_0+512, vb, tid, (int*)smem);
  gbar(P.flags, P.gen, ++g);

  for (int t = 0; t < TT; ++t){
    int init = (t == 0) ? 1 : 0;
    // A: bnlif l0 (+ aggfin of previous t)
    int nvb = init ? 512 : 1024;
    for (int vb = bid; vb < nvb; vb += GRID){
      if (vb < 512)
        bnlif_dev(vb*256+tid, 6, P.hmax0, P.S12_0, P.S12_0+512, P.g0, P.b0,
                  P.lp[0][0], P.lp[0][1], P.lp[0][2], P.lp[0][3],
                  P.stM0, P.stT0, P.stR0, P.scatH, 0, P.pk0, init, tid);
      else
        aggfin_dev(P.aggA, P.aggB, P.gm, P.bm, P.pooled + (size_t)(t-1)*1024, vb-512, tid, smem);
    }
    gbar(P.flags, P.gen, ++g);

    layer_body<1>(P, P.pk0, P.wcH1, P.g1, P.b1,
                  P.lp[1][0], P.lp[1][1], P.lp[1][2], P.lp[1][3],
                  P.stM1, P.stT1, P.stR1, P.pk1,  64, 128, 7,   0,  64, init, g, bid, tid, smem);
    layer_body<2>(P, P.pk1, P.wcH2, P.g2, P.b2,
                  P.lp[2][0], P.lp[2][1], P.lp[2][2], P.lp[2][3],
                  P.stM2, P.stT2, P.stR2, P.pk2, 128, 256, 8,  64, 192, init, g, bid, tid, smem);
    layer_body<4>(P, P.pk2, P.wcH3, P.g3, P.b3,
                  P.lp[3][0], P.lp[3][1], P.lp[3][2], P.lp[3][3],
                  P.stM3, P.stT3, P.stR3, P.pk3, 256, 512, 9, 192, 448, init, g, bid, tid, smem);

    // E: agg split-K MFMA
    for (int vb = bid; vb < 512; vb += GRID){
      int part = vb >> 8, tl = vb & 255, tm = tl >> 3, tn = tl & 7;
      mfma_dev(P.scatH, CATC, P.WmH, (size_t)512*960, 960, part ? P.aggB : P.aggA, 512,
               480, part*480, tm*64, tn*64, tid);
    }
    gbar(P.flags, P.gen, ++g);
  }

  // tail: aggfin(t=2) then final
  for (int vb = bid; vb < 512; vb += GRID)
    aggfin_dev(P.aggA, P.aggB, P.gm, P.bm, P.pooled + 2048, vb, tid, smem);
  gbar(P.flags, P.gen, ++g);

  for (int vb = bid; vb < 4; vb += GRID){
    int i = vb*256 + tid;
    int b = i / 512, o = i - b*512;
    float t0 = P.tw[0], t1 = P.tw[1], t2 = P.tw[2];
    float mx = fmaxf(t0, fmaxf(t1, t2));
    float e0 = expf(t0-mx), e1 = expf(t1-mx), e2 = expf(t2-mx);
    float den = e0 + e1 + e2;
    float v = (e0/den)*P.pooled[(0*BB+b)*512+o]
            + (e1/den)*P.pooled[(1*BB+b)*512+o]
            + (e2/den)*P.pooled[(2*BB+b)*512+o];
    P.out[i] = (v - P.lftb[o] > 0.f) ? 1.f : 0.f;
  }
}

// ===================== host =====================
extern "C" void kernel_launch(void* const* d_in, const int* in_sizes, int n_in,
                              void* d_out, int out_size, void* d_ws, size_t ws_size,
                              hipStream_t stream)
{
  (void)in_sizes; (void)n_in; (void)out_size; (void)ws_size;
  MegaP P;
  P.x  = (const float*)d_in[0];
  const float* Wl[4] = {(const float*)d_in[1],(const float*)d_in[4],(const float*)d_in[7],(const float*)d_in[10]};
  P.W0 = Wl[0]; P.W1 = Wl[1]; P.W2 = Wl[2]; P.W3 = Wl[3];
  P.g0 = (const float*)d_in[2];  P.b0 = (const float*)d_in[3];
  P.g1 = (const float*)d_in[5];  P.b1 = (const float*)d_in[6];
  P.g2 = (const float*)d_in[8];  P.b2 = (const float*)d_in[9];
  P.g3 = (const float*)d_in[11]; P.b3 = (const float*)d_in[12];
  P.Wm = (const float*)d_in[13];
  P.gm = (const float*)d_in[14];
  P.bm = (const float*)d_in[15];
  for (int l = 0; l < 4; ++l)
    for (int q = 0; q < 4; ++q)
      P.lp[l][q] = (const float*)d_in[16 + l*4 + q];
  P.lftb = (const float*)d_in[35];   // lf tb
  P.tw   = (const float*)d_in[36];

  char* pw = (char*)d_ws;
  auto alloc = [&](size_t bytes)->char* {
    char* r = pw; pw += (bytes + 255) & ~(size_t)255; return r;
  };
  P.f0     = (float*)alloc((size_t)ROWS*3*sizeof(float));
  P.x2     = (float*)alloc((size_t)ROWS*sizeof(float));
  P.idx0   = (int*)  alloc((size_t)ROWS*KNN*sizeof(int));
  P.idxS   = (int*)  alloc((size_t)ROWS*KNN*sizeof(int));
  P.AB     = (float*)alloc((size_t)ROWS*1024*sizeof(float));
  P.hmax0  = (float*)alloc((size_t)ROWS*64*sizeof(float));
  P.hmaxS  = (float*)alloc((size_t)ROWS*512*sizeof(float));  // doubles as aggB
  P.aggA   = (float*)alloc((size_t)ROWS*512*sizeof(float));
  P.scatH  = (short*)alloc((size_t)ROWS*CATC*sizeof(short));
  P.S12_0  = (double*)alloc(1024*sizeof(double));
  P.S12    = (double*)alloc(1024*sizeof(double));
  P.pooled = (float*)alloc((size_t)TT*BB*512*sizeof(float));
  P.pk0 = (ull*)alloc((size_t)ROWS*1*sizeof(ull));
  P.pk1 = (ull*)alloc((size_t)ROWS*2*sizeof(ull));
  P.pk2 = (ull*)alloc((size_t)ROWS*4*sizeof(ull));
  P.pk3 = (ull*)alloc((size_t)ROWS*8*sizeof(ull));
  P.wc0  = (float*)alloc((size_t)2*64*3*sizeof(float));
  P.wcH1 = (short*)alloc((size_t)3*256*64*sizeof(short));
  P.wcH2 = (short*)alloc((size_t)3*512*128*sizeof(short));
  P.wcH3 = (short*)alloc((size_t)3*1024*256*sizeof(short));
  P.WmH  = (short*)alloc((size_t)3*512*960*sizeof(short));
  P.stM0 = (float*)alloc((size_t)ROWS*64*sizeof(float));
  P.stT0 = (float*)alloc((size_t)ROWS*64*sizeof(float));
  P.stR0 = (float*)alloc((size_t)ROWS*64*sizeof(float));
  P.stM1 = (float*)alloc((size_t)ROWS*128*sizeof(float));
  P.stT1 = (float*)alloc((size_t)ROWS*128*sizeof(float));
  P.stR1 = (float*)alloc((size_t)ROWS*128*sizeof(float));
  P.stM2 = (float*)alloc((size_t)ROWS*256*sizeof(float));
  P.stT2 = (float*)alloc((size_t)ROWS*256*sizeof(float));
  P.stR2 = (float*)alloc((size_t)ROWS*256*sizeof(float));
  P.stM3 = (float*)alloc((size_t)ROWS*512*sizeof(float));
  P.stT3 = (float*)alloc((size_t)ROWS*512*sizeof(float));
  P.stR3 = (float*)alloc((size_t)ROWS*512*sizeof(float));
  unsigned* bar = (unsigned*)alloc(4096);
  P.flags = bar;
  P.gen   = bar + 1024;
  P.aggB  = P.hmaxS;   // lifetime-disjoint alias
  P.out   = (float*)d_out;

  hipMemsetAsync(bar, 0, 4096, stream);
  k_mega<<<GRID, 256, 0, stream>>>(P);
}

// Round 7
// 754.120 us; speedup vs baseline: 6.3293x; 6.3293x over previous
//
#include <hip/hip_runtime.h>
#include <math.h>

#define NPTS 1024
#define BB 2
#define KNN 20
#define ROWS 2048
#define CATC 960
#define TT 3
#define GRID 512
typedef unsigned long long ull;
typedef __attribute__((ext_vector_type(8))) short bf16x8;
typedef __attribute__((ext_vector_type(4))) float f32x4;

__device__ __forceinline__ float lrelu_f(float x){ return x >= 0.f ? x : 0.2f*x; }
__device__ __forceinline__ unsigned short f2bf(float f){
  unsigned u = __float_as_uint(f);
  return (unsigned short)((u + 0x7FFFu + ((u >> 16) & 1u)) >> 16);
}
__device__ __forceinline__ float bf2f(unsigned short h){ return __uint_as_float(((unsigned)h) << 16); }

// ---- coherent (device-visible) RELAXED stores/loads: no fences, no cache invalidation ----
__device__ __forceinline__ void stg_f32(float* p, float v){ __hip_atomic_store(p, v, __ATOMIC_RELAXED, __HIP_MEMORY_SCOPE_AGENT); }
__device__ __forceinline__ void stg_u32(unsigned* p, unsigned v){ __hip_atomic_store(p, v, __ATOMIC_RELAXED, __HIP_MEMORY_SCOPE_AGENT); }
__device__ __forceinline__ void stg_u64(ull* p, ull v){ __hip_atomic_store(p, v, __ATOMIC_RELAXED, __HIP_MEMORY_SCOPE_AGENT); }
__device__ __forceinline__ void stg_f64(double* p, double v){ __hip_atomic_store(p, v, __ATOMIC_RELAXED, __HIP_MEMORY_SCOPE_AGENT); }
__device__ __forceinline__ unsigned ldg_u32(const unsigned* p){ return __hip_atomic_load(p, __ATOMIC_RELAXED, __HIP_MEMORY_SCOPE_AGENT); }

// ===================== relaxed grid barrier =====================
__device__ __forceinline__ void gbar(unsigned* flags, unsigned* gen, unsigned g){
  asm volatile("s_waitcnt vmcnt(0)" ::: "memory");   // drain this wave's stores
  __syncthreads();                                   // join (drains all waves)
  if (blockIdx.x == 0){
    for (int i = threadIdx.x; i < GRID; i += 256)
      if (i) while (ldg_u32(&flags[i]) < g) __builtin_amdgcn_s_sleep(4);
    __syncthreads();
    if (threadIdx.x == 0) stg_u32(gen, g);
  } else {
    if (threadIdx.x == 0){
      stg_u32(&flags[blockIdx.x], g);
      while (ldg_u32(gen) < g) __builtin_amdgcn_s_sleep(4);
    }
    __syncthreads();
  }
}

// ===================== param struct =====================
struct MegaP {
  const float *x,*W0,*W1,*W2,*W3,*Wm;
  const float *gl[4],*bl[4],*gm,*bm,*tw,*lftb;
  const float *lp[4][4];
  int *idx0,*idxS;
  float *AB0,*hmax0;
  double *S12;            // 10 instances of 1024 doubles: [0]=layer0, [1+t*3+li]
  float *ABl[3][3];       // [t][li]
  short *scatH[3];
  ull *pk[3][4];          // [t][layer-output 0..3]
  float *aggA[3],*aggB[3],*pooled;
  short *wcH1,*wcH2,*wcH3,*WmH;
  float *stM[4],*stT[4],*stR[4];
  float *out;
  unsigned *flags,*gen;
};

// ===================== MFMA bf16 3-split GEMM (LDS-free, 64x64 tile, sc1 out) =====================
__device__ __forceinline__ void mfma_dev(const short* __restrict__ A, int lda,
    const short* __restrict__ B3, size_t sStride, int ldb,
    float* __restrict__ C, int ldc, int K, int kb, int bm, int bn, int tid)
{
  const int wave = tid >> 6, lane = tid & 63;
  const int wm = (wave >> 1) << 5, wn = (wave & 1) << 5;
  const int rr = lane & 15, kq = (lane >> 4) << 3;
  f32x4 acc[2][2] = {};
  const short* Ap = A + (size_t)(bm + wm + rr)*lda + kb + kq;
  const short* Bp = B3 + (size_t)(bn + wn + rr)*ldb + kb + kq;
  for (int k0 = 0; k0 < K; k0 += 32) {
    bf16x8 a0 = *(const bf16x8*)(Ap + k0);
    bf16x8 a1 = *(const bf16x8*)(Ap + (size_t)16*lda + k0);
#pragma unroll
    for (int s = 0; s < 3; ++s) {
      bf16x8 b0 = *(const bf16x8*)(Bp + (size_t)s*sStride + k0);
      bf16x8 b1 = *(const bf16x8*)(Bp + (size_t)s*sStride + (size_t)16*ldb + k0);
      acc[0][0] = __builtin_amdgcn_mfma_f32_16x16x32_bf16(a0, b0, acc[0][0], 0, 0, 0);
      acc[0][1] = __builtin_amdgcn_mfma_f32_16x16x32_bf16(a0, b1, acc[0][1], 0, 0, 0);
      acc[1][0] = __builtin_amdgcn_mfma_f32_16x16x32_bf16(a1, b0, acc[1][0], 0, 0, 0);
      acc[1][1] = __builtin_amdgcn_mfma_f32_16x16x32_bf16(a1, b1, acc[1][1], 0, 0, 0);
    }
  }
  const int drb = (lane >> 4) << 2;
#pragma unroll
  for (int i = 0; i < 2; ++i)
#pragma unroll
    for (int j = 0; j < 2; ++j)
#pragma unroll
      for (int t = 0; t < 4; ++t)
        stg_f32(&C[(size_t)(bm + wm + i*16 + drb + t)*ldc + bn + wn + j*16 + rr], acc[i][j][t]);
}

// ===================== wave-level popcount KNN (idx block-local: plain stores) =====================
template<int W>
__device__ __forceinline__ void knn_wave(const ull* __restrict__ pk, int* __restrict__ idx,
                                         int row, int lane)
{
  const int n = row & (NPTS-1), b = row >> 10;
  const ull* pb = pk + (size_t)b*NPTS*W;
  ull cw[W]; int pn = 0;
#pragma unroll
  for (int w=0; w<W; ++w){ cw[w] = pb[(size_t)n*W + w]; pn += __popcll(cw[w]); }
  unsigned keys[16];
#pragma unroll 4
  for (int i=0;i<16;++i){
    int m = lane + (i<<6);
    int inner=0, pm=0;
#pragma unroll
    for (int w=0;w<W;++w){
      ull rm = pb[(size_t)m*W + w];
      inner += __popcll(rm & cw[w]);
      pm    += __popcll(rm);
    }
    int d = 2*inner - pn - pm;
    keys[i] = ((unsigned)(d+1024)<<11) | (unsigned)(NPTS-1-m);
  }
  unsigned lmax = keys[0];
#pragma unroll
  for (int i=1;i<16;++i) lmax = keys[i]>lmax ? keys[i] : lmax;
  unsigned mywin = 0;
  for (int s=0;s<KNN;++s){
    unsigned v = lmax;
#pragma unroll
    for (int off=1; off<64; off<<=1){ unsigned o = __shfl_xor(v, off, 64); if (o>v) v=o; }
    if (lane == s) mywin = (unsigned)(NPTS-1) - (v & 0x7FFu);
    if (lmax == v){
#pragma unroll
      for (int i=0;i<16;++i) if (keys[i]==v) keys[i]=0u;
      lmax = keys[0];
#pragma unroll
      for (int i=1;i<16;++i) lmax = keys[i]>lmax ? keys[i] : lmax;
    }
  }
  if (lane < KNN) idx[(size_t)row*KNN + lane] = (int)mywin;
}

// ===================== layer-0 KNN, self-contained (reads x only; exact ref op order) =====================
__device__ __forceinline__ void knn0_wave(const float* __restrict__ x, int* __restrict__ idx,
                                          int row, int lane)
{
  const int n = row & (NPTS-1), b = row >> 10;
  const float* xb = x + (size_t)b*3*NPTS;
  float fn0 = xb[n], fn1 = xb[NPTS+n], fn2 = xb[2*NPTS+n];
  float x2n = __fadd_rn(__fadd_rn(__fmul_rn(fn0,fn0), __fmul_rn(fn1,fn1)), __fmul_rn(fn2,fn2));
  ull keys[16];
#pragma unroll 4
  for (int i=0;i<16;++i){
    int m = lane + (i<<6);
    float a0 = xb[m], a1 = xb[NPTS+m], a2 = xb[2*NPTS+m];
    float x2m = __fadd_rn(__fadd_rn(__fmul_rn(a0,a0), __fmul_rn(a1,a1)), __fmul_rn(a2,a2));
    float inner = __fadd_rn(__fadd_rn(__fmul_rn(fn0,a0), __fmul_rn(fn1,a1)), __fmul_rn(fn2,a2));
    float v = __fsub_rn(__fsub_rn(__fmul_rn(2.f,inner), x2n), x2m);
    unsigned u = __float_as_uint(v);
    u = (u & 0x80000000u) ? ~u : (u | 0x80000000u);
    keys[i] = ((ull)u << 32) | (unsigned)(NPTS-1-m);
  }
  ull lmax = keys[0];
#pragma unroll
  for (int i=1;i<16;++i) lmax = keys[i]>lmax ? keys[i] : lmax;
  unsigned mywin = 0;
  for (int s=0;s<KNN;++s){
    ull v = lmax;
#pragma unroll
    for (int off=1; off<64; off<<=1){ ull o = __shfl_xor(v, off, 64); if (o>v) v=o; }
    if (lane == s) mywin = (unsigned)(NPTS-1) - (unsigned)(v & 0xFFFFFFFFull);
    if (lmax == v){
#pragma unroll
      for (int i=0;i<16;++i) if (keys[i]==v) keys[i]=0ull;
      lmax = keys[0];
#pragma unroll
      for (int i=1;i<16;++i) lmax = keys[i]>lmax ? keys[i] : lmax;
    }
  }
  if (lane < KNN) idx[(size_t)row*KNN + lane] = (int)mywin;
}

// ===================== conv0: K=3 fp32, reads x + W0 directly, sc1 out =====================
__device__ __forceinline__ void conv0_dev(const float* __restrict__ x, const float* __restrict__ W0,
    float* __restrict__ AB0, int tile, int tid, float* sm)
{
  float (*As)[64] = (float(*)[64])sm;          // [3][64]
  float (*Bs)[64] = (float(*)[64])(sm + 3*64); // [3][64]
  int bm = (tile >> 1) * 64, bn = (tile & 1) * 64;
  int b = bm >> 10, n0 = bm & (NPTS-1);
  if (tid < 192){ int k = tid >> 6, r = tid & 63; As[k][r] = x[(size_t)b*3072 + k*NPTS + n0 + r]; }
  if (tid >= 64){
    int k = (tid - 64) >> 6, c = (tid - 64) & 63; int row = bn + c;
    Bs[k][c] = (row < 64) ? __fadd_rn(W0[(size_t)row*6+k], W0[(size_t)row*6+3+k])
                          : W0[(size_t)(row-64)*6+k];
  }
  __syncthreads();
  const int tx = tid & 15, ty = tid >> 4;
  float acc[4][4] = {};
#pragma unroll
  for (int kk = 0; kk < 3; ++kk){
    float ar[4], br[4];
#pragma unroll
    for (int i=0;i<4;++i) ar[i] = As[kk][ty*4+i];
#pragma unroll
    for (int j=0;j<4;++j) br[j] = Bs[kk][tx*4+j];
#pragma unroll
    for (int i=0;i<4;++i)
#pragma unroll
      for (int j=0;j<4;++j) acc[i][j] = fmaf(ar[i], br[j], acc[i][j]);
  }
#pragma unroll
  for (int i=0;i<4;++i)
#pragma unroll
    for (int j=0;j<4;++j)
      stg_f32(&AB0[(size_t)(bm+ty*4+i)*128 + bn+tx*4+j], acc[i][j]);
  __syncthreads();
}

// ===================== weight split (3x bf16), pair-packed sc1 stores =====================
__device__ __forceinline__ void wsplit_store(float w, short* dst, size_t NK, size_t e, int tid){
  unsigned short h1 = f2bf(w); float f1 = bf2f(h1);
  float r1 = w - f1;
  unsigned short h2 = f2bf(r1); float f2v = bf2f(h2);
  unsigned short h3 = f2bf(r1 - f2v);
  int p1=h1, p2=h2, p3=h3;
  int q1=__shfl_xor(p1,1), q2=__shfl_xor(p2,1), q3=__shfl_xor(p3,1);
  if (!(tid & 1)){
    stg_u32((unsigned*)(dst + e),        (unsigned)(unsigned short)p1 | ((unsigned)(unsigned short)q1<<16));
    stg_u32((unsigned*)(dst + NK + e),   (unsigned)(unsigned short)p2 | ((unsigned)(unsigned short)q2<<16));
    stg_u32((unsigned*)(dst + 2*NK + e), (unsigned)(unsigned short)p3 | ((unsigned)(unsigned short)q3<<16));
  }
}
__device__ __forceinline__ void wcatsplit(const float* __restrict__ W, short* __restrict__ dst,
                                          int O, int C, size_t e, int tid){
  int rr = (int)(e / C), cc = (int)(e - (size_t)rr*C);
  float w = (rr < O) ? __fadd_rn(W[(size_t)rr*2*C + cc], W[(size_t)rr*2*C + C + cc])
                     : W[(size_t)(rr-O)*2*C + cc];
  wsplit_store(w, dst, (size_t)2*O*C, e, tid);
}

// ===================== gather0 (layer 0): hmax0 block-local plain, stats atomic =====================
__device__ __forceinline__ void gather0_dev(const MegaP& P, int bid, int tid, int* sidx){
  int base = bid*4;
  for (int i = tid; i < 4*KNN; i += 256) sidx[i] = P.idx0[(size_t)base*KNN + i];
  __syncthreads();
  double* S1 = P.S12; double* S2 = P.S12 + 512;
  for (int o = tid; o < 64; o += 256){
    double ts1=0.0, ts2=0.0;
    for (int r=0;r<4;++r){
      int row = base+r, b = row>>10;
      float bc = P.AB0[(size_t)row*128 + 64 + o];
      float mx = -INFINITY; double s1=0.0, s2=0.0;
#pragma unroll
      for (int k=0;k<KNN;++k){
        int m = sidx[r*KNN+k];
        float a = P.AB0[((size_t)(b*NPTS+m))*128 + o];
        mx = fmaxf(mx,a); s1 += (double)a; s2 += (double)a*(double)a;
      }
      P.hmax0[(size_t)row*64 + o] = mx - bc;    // plain: same block reads in PA
      ts1 += s1 - (double)KNN*(double)bc;
      ts2 += s2 - 2.0*(double)bc*s1 + (double)KNN*(double)bc*(double)bc;
    }
    atomicAdd(&S1[o], ts1);
    atomicAdd(&S2[o], ts2);
  }
  __syncthreads();
}

// ===================== LIF math (shared) =====================
__device__ __forceinline__ float lif_step(float h, int o, size_t i, int init,
    const double* S1, const double* S2,
    const float* gv, const float* bv,
    const float* pmd, const float* pta, const float* prd, const float* ptb,
    float* sM, float* sT, float* sR)
{
  double cnt = (double)ROWS * (double)KNN;
  double mu = S1[o] / cnt;
  double vv = S2[o] / cnt - mu*mu;
  float mean = (float)mu;
  float inv  = 1.f / sqrtf((float)vv + 1e-5f);
  h = ((h - mean) * inv) * gv[o] + bv[o];
  h = lrelu_f(h);
  float md = fminf(fmaxf(pmd[o], 0.1f), 0.99f);
  float ta = fminf(fmaxf(pta[o], 0.001f), 0.1f);
  float rd = fminf(fmaxf(prd[o], 0.1f), 0.95f);
  float tb = ptb[o];
  float M, T, R;
  if (init) { M = 0.f; T = tb; R = 0.f; }
  else      { M = sM[i]; T = sT[i]; R = sR[i]; }
  float xv = (R <= 0.f) ? h : 0.f;
  M = M * md * (1.f - R) + xv;
  float sp = (M - T > 0.f) ? 1.f : 0.f;
  M = M * (1.f - sp);
  R = R * rd + sp;
  T = tb + (T + ta*sp - tb) * 0.95f;
  sM[i] = M; sT[i] = T; sR[i] = R;
  return sp;
}

// spike emit: pair-packed sc1 to scatH + ballot sc1 to pk
__device__ __forceinline__ void emit_spike(float sp, short* scat, size_t row, int off, int o,
                                           ull* pk, size_t i, int tid)
{
  int sv = (sp != 0.f) ? 0x3F80 : 0;
  int ov = __shfl_xor(sv, 1);
  if (!(tid & 1))
    stg_u32((unsigned*)(scat + row*CATC + off + o), (unsigned)(unsigned short)sv | ((unsigned)ov<<16));
  ull ball = __ballot(sp != 0.f);
  if ((tid & 63) == 0) stg_u64(&pk[i >> 6], ball);
}

// ===================== aggfin (per channel), pooled sc1 =====================
__device__ __forceinline__ void aggfin_dev(const float* __restrict__ pA, const float* __restrict__ pB,
    const float* __restrict__ gm, const float* __restrict__ bmv, float* __restrict__ pooled,
    int o, int tid, char* smraw)
{
  double* sd1 = (double*)smraw; double* sd2 = sd1 + 256;
  float* sm0 = (float*)(sd2 + 256); float* sm1 = sm0 + 256;
  double s1=0.0, s2=0.0; float m0=-INFINITY, m1=-INFINITY;
  for (int r=tid; r<ROWS; r+=256){
    float v = __fadd_rn(pA[(size_t)r*512+o], pB[(size_t)r*512+o]);
    s1 += (double)v; s2 += (double)v*(double)v;
    if (r < NPTS) m0 = fmaxf(m0, v); else m1 = fmaxf(m1, v);
  }
  sd1[tid]=s1; sd2[tid]=s2; sm0[tid]=m0; sm1[tid]=m1;
  __syncthreads();
  for (int off=128; off>0; off>>=1){
    if (tid<off){
      sd1[tid]+=sd1[tid+off]; sd2[tid]+=sd2[tid+off];
      sm0[tid]=fmaxf(sm0[tid],sm0[tid+off]);
      sm1[tid]=fmaxf(sm1[tid],sm1[tid+off]);
    }
    __syncthreads();
  }
  if (tid==0){
    double mean = sd1[0]/(double)ROWS;
    float var = (float)(sd2[0]/(double)ROWS - mean*mean);
    float m = (float)mean;
    float inv = 1.f/sqrtf(var + 1e-5f);
    stg_f32(&pooled[o],       lrelu_f(((sm0[0]-m)*inv)*gm[o] + bmv[o]));
    stg_f32(&pooled[512 + o], lrelu_f(((sm1[0]-m)*inv)*gm[o] + bmv[o]));
  }
  __syncthreads();
}

// ===================== per-layer body: PB (knn+conv) | PCa (gather) | PCb (bnlif) =====================
template<int LI, int W>
__device__ void layer_v2(const MegaP& P, int t, int init, unsigned& g,
                         int bid, int tid, char* smem)
{
  const int C = 64 << LI, O = 128 << LI, twoO = 2*O, ntn = twoO >> 6, oShift = 7 + LI;
  const int offIn  = (LI==0) ? 0 : (LI==1 ? 64 : 192);
  const int offOut = (LI==0) ? 64 : (LI==1 ? 192 : 448);
  const ull* pk = P.pk[t][LI];
  short* scat = P.scatH[t];
  float* AB = P.ABl[t][LI];
  double* S12 = P.S12 + (size_t)(1 + t*3 + LI)*1024;
  const short* wcH = (LI==0) ? P.wcH1 : (LI==1 ? P.wcH2 : P.wcH3);
  // PB: knn (512 vb) + conv tiles
  int nvb = 512 + 32*ntn;
  for (int vb = bid; vb < nvb; vb += GRID){
    if (vb < 512) knn_wave<W>(pk, P.idxS, vb*4 + (tid>>6), tid & 63);
    else {
      int id = vb - 512, tm = id/ntn, tn = id - tm*ntn;
      mfma_dev(scat + offIn, CATC, wcH, (size_t)twoO*C, C, AB, twoO, C, 0, tm*64, tn*64, tid);
    }
  }
  gbar(P.flags, P.gen, ++g);
  // PCa: gather into LDS + global stats atomics
  int* sidx = (int*)smem;
  float* hls = (float*)(smem + 512);
  {
    int base = bid*4;
    for (int i = tid; i < 4*KNN; i += 256) sidx[i] = P.idxS[(size_t)base*KNN + i];
    __syncthreads();
    double* S1 = S12; double* S2 = S12 + 512;
    for (int o = tid; o < O; o += 256){
      double ts1=0.0, ts2=0.0;
      for (int r=0;r<4;++r){
        int row = base+r, b = row>>10;
        float bc = AB[(size_t)row*twoO + O + o];
        float mx = -INFINITY; double s1=0.0, s2=0.0;
#pragma unroll
        for (int k=0;k<KNN;++k){
          int m = sidx[r*KNN+k];
          float a = AB[((size_t)(b*NPTS+m))*twoO + o];
          mx = fmaxf(mx,a); s1 += (double)a; s2 += (double)a*(double)a;
        }
        hls[r*O+o] = mx - bc;
        ts1 += s1 - (double)KNN*(double)bc;
        ts2 += s2 - 2.0*(double)bc*s1 + (double)KNN*(double)bc*(double)bc;
      }
      atomicAdd(&S1[o], ts1);
      atomicAdd(&S2[o], ts2);
    }
  }
  gbar(P.flags, P.gen, ++g);
  // PCb: bnlif from LDS hmax + global stats
  {
    const double* S1 = S12; const double* S2 = S12 + 512;
    int base = bid*4;
    for (int e = tid; e < 4*O; e += 256){
      int r = e >> oShift, o = e & (O-1);
      size_t row = (size_t)(base + r);
      size_t i = row*O + o;
      float sp = lif_step(hls[r*O+o], o, i, init, S1, S2,
                          P.gl[LI+1], P.bl[LI+1],
                          P.lp[LI+1][0], P.lp[LI+1][1], P.lp[LI+1][2], P.lp[LI+1][3],
                          P.stM[LI+1], P.stT[LI+1], P.stR[LI+1]);
      emit_spike(sp, scat, row, offOut, o, P.pk[t][LI+1], i, tid);
    }
  }
  gbar(P.flags, P.gen, ++g);
}

// ===================== THE mega kernel =====================
__global__ __launch_bounds__(256, 2) void k_mega(MegaP P)
{
  __shared__ __align__(16) char smem[8704];
  const int bid = blockIdx.x, tid = threadIdx.x;
  unsigned g = 0;

  // ---- P0: knn0 + conv0 + S12 zero + weight splits ----
  for (int vb = bid; vb < 3850; vb += GRID){
    if (vb < 512)        knn0_wave(P.x, P.idx0, vb*4 + (tid>>6), tid & 63);
    else if (vb < 576)   conv0_dev(P.x, P.W0, P.AB0, vb - 512, tid, (float*)smem);
    else if (vb < 586){  int inst = vb - 576;
                         for (int j = tid; j < 1024; j += 256) stg_f64(P.S12 + (size_t)inst*1024 + j, 0.0); }
    else if (vb < 650)   wcatsplit(P.W1, P.wcH1, 128,  64, (size_t)(vb-586)*256 + tid, tid);
    else if (vb < 906)   wcatsplit(P.W2, P.wcH2, 256, 128, (size_t)(vb-650)*256 + tid, tid);
    else if (vb < 1930)  wcatsplit(P.W3, P.wcH3, 512, 256, (size_t)(vb-906)*256 + tid, tid);
    else {               size_t e = (size_t)(vb-1930)*256 + tid;
                         wsplit_store(P.Wm[e], P.WmH, (size_t)512*960, e, tid); }
  }
  gbar(P.flags, P.gen, ++g);

  // ---- P1: gather0 ----
  gather0_dev(P, bid, tid, (int*)smem);
  gbar(P.flags, P.gen, ++g);

  for (int t = 0; t < TT; ++t){
    int init = (t == 0) ? 1 : 0;
    // ---- PA: lif0 (+ aggfin of t-1) ----
    {
      int i = bid*256 + tid;
      int o = i & 63;
      size_t row = (size_t)(i >> 6);
      float sp = lif_step(P.hmax0[i], o, (size_t)i, init, P.S12, P.S12 + 512,
                          P.gl[0], P.bl[0],
                          P.lp[0][0], P.lp[0][1], P.lp[0][2], P.lp[0][3],
                          P.stM[0], P.stT[0], P.stR[0]);
      emit_spike(sp, P.scatH[t], row, 0, o, P.pk[t][0], (size_t)i, tid);
      if (t > 0)
        aggfin_dev(P.aggA[t-1], P.aggB[t-1], P.gm, P.bm, P.pooled + (size_t)(t-1)*1024, bid, tid, smem);
    }
    gbar(P.flags, P.gen, ++g);

    layer_v2<0,1>(P, t, init, g, bid, tid, smem);
    layer_v2<1,2>(P, t, init, g, bid, tid, smem);
    layer_v2<2,4>(P, t, init, g, bid, tid, smem);

    // ---- PE: agg split-K MFMA ----
    {
      int part = bid >> 8, tl = bid & 255, tm = tl >> 3, tn = tl & 7;
      mfma_dev(P.scatH[t], CATC, P.WmH, (size_t)512*960, 960,
               part ? P.aggB[t] : P.aggA[t], 512, 480, part*480, tm*64, tn*64, tid);
    }
    gbar(P.flags, P.gen, ++g);
  }

  // ---- tail: aggfin(t=2) ----
  aggfin_dev(P.aggA[2], P.aggB[2], P.gm, P.bm, P.pooled + 2048, bid, tid, smem);
  gbar(P.flags, P.gen, ++g);

  // ---- final ----
  if (bid < 4){
    int i = bid*256 + tid;
    int b = i / 512, o = i - b*512;
    float t0 = P.tw[0], t1 = P.tw[1], t2 = P.tw[2];
    float mx = fmaxf(t0, fmaxf(t1, t2));
    float e0 = expf(t0-mx), e1 = expf(t1-mx), e2 = expf(t2-mx);
    float den = e0 + e1 + e2;
    float v = (e0/den)*P.pooled[(0*BB+b)*512+o]
            + (e1/den)*P.pooled[(1*BB+b)*512+o]
            + (e2/den)*P.pooled[(2*BB+b)*512+o];
    P.out[i] = (v - P.lftb[o] > 0.f) ? 1.f : 0.f;
  }
}

// ===================== host =====================
extern "C" void kernel_launch(void* const* d_in, const int* in_sizes, int n_in,
                              void* d_out, int out_size, void* d_ws, size_t ws_size,
                              hipStream_t stream)
{
  (void)in_sizes; (void)n_in; (void)out_size; (void)ws_size;
  MegaP P;
  P.x  = (const float*)d_in[0];
  P.W0 = (const float*)d_in[1];  P.gl[0] = (const float*)d_in[2];  P.bl[0] = (const float*)d_in[3];
  P.W1 = (const float*)d_in[4];  P.gl[1] = (const float*)d_in[5];  P.bl[1] = (const float*)d_in[6];
  P.W2 = (const float*)d_in[7];  P.gl[2] = (const float*)d_in[8];  P.bl[2] = (const float*)d_in[9];
  P.W3 = (const float*)d_in[10]; P.gl[3] = (const float*)d_in[11]; P.bl[3] = (const float*)d_in[12];
  P.Wm = (const float*)d_in[13];
  P.gm = (const float*)d_in[14];
  P.bm = (const float*)d_in[15];
  for (int l = 0; l < 4; ++l)
    for (int q = 0; q < 4; ++q)
      P.lp[l][q] = (const float*)d_in[16 + l*4 + q];
  P.lftb = (const float*)d_in[35];
  P.tw   = (const float*)d_in[36];

  char* pw = (char*)d_ws;
  auto alloc = [&](size_t bytes)->char* {
    char* r = pw; pw += (bytes + 255) & ~(size_t)255; return r;
  };
  P.idx0  = (int*)   alloc((size_t)ROWS*KNN*sizeof(int));
  P.idxS  = (int*)   alloc((size_t)ROWS*KNN*sizeof(int));
  P.AB0   = (float*) alloc((size_t)ROWS*128*sizeof(float));
  P.hmax0 = (float*) alloc((size_t)ROWS*64*sizeof(float));
  P.S12   = (double*)alloc((size_t)10*1024*sizeof(double));
  for (int t = 0; t < 3; ++t)
    for (int li = 0; li < 3; ++li)
      P.ABl[t][li] = (float*)alloc((size_t)ROWS*(256 << li)*sizeof(float));
  for (int t = 0; t < 3; ++t) P.scatH[t] = (short*)alloc((size_t)ROWS*CATC*sizeof(short));
  int Wn[4] = {1, 2, 4, 8};
  for (int t = 0; t < 3; ++t)
    for (int l = 0; l < 4; ++l)
      P.pk[t][l] = (ull*)alloc((size_t)ROWS*Wn[l]*sizeof(ull));
  for (int t = 0; t < 3; ++t){
    P.aggA[t] = (float*)alloc((size_t)ROWS*512*sizeof(float));
    P.aggB[t] = (float*)alloc((size_t)ROWS*512*sizeof(float));
  }
  P.pooled = (float*)alloc((size_t)TT*BB*512*sizeof(float));
  P.wcH1 = (short*)alloc((size_t)3*2*128*64*sizeof(short));
  P.wcH2 = (short*)alloc((size_t)3*2*256*128*sizeof(short));
  P.wcH3 = (short*)alloc((size_t)3*2*512*256*sizeof(short));
  P.WmH  = (short*)alloc((size_t)3*512*960*sizeof(short));
  int Oo[4] = {64, 128, 256, 512};
  for (int l = 0; l < 4; ++l){
    P.stM[l] = (float*)alloc((size_t)ROWS*Oo[l]*sizeof(float));
    P.stT[l] = (float*)alloc((size_t)ROWS*Oo[l]*sizeof(float));
    P.stR[l] = (float*)alloc((size_t)ROWS*Oo[l]*sizeof(float));
  }
  unsigned* bar = (unsigned*)alloc(4096);
  P.flags = bar;
  P.gen   = bar + 1024;
  P.out   = (float*)d_out;

  hipMemsetAsync(bar, 0, 4096, stream);
  k_mega<<<GRID, 256, 0, stream>>>(P);
}